// Round 2
// baseline (5165.283 us; speedup 1.0000x reference)
//
#include <hip/hip_runtime.h>

typedef _Float16 h2 __attribute__((ext_vector_type(2)));
typedef _Float16 h8 __attribute__((ext_vector_type(8)));

#define U_DIM 256
#define M_DIM 256
#define T_DIM 512

#if defined(__has_builtin)
#if __has_builtin(__builtin_amdgcn_fdot2)
#define HAVE_FDOT2 1
#endif
#endif

__device__ __forceinline__ float fdot2f(h2 a, h2 b, float c) {
#ifdef HAVE_FDOT2
  return __builtin_amdgcn_fdot2(a, b, c, false);
#else
  return fmaf((float)a[0], (float)b[0], fmaf((float)a[1], (float)b[1], c));
#endif
}

__device__ __forceinline__ float fast_sigmoid(float z) {
  return __builtin_amdgcn_rcpf(1.f + __expf(-z));
}
__device__ __forceinline__ float fast_tanh(float z) {
  // tanh(z) = 2/(1+exp(-2z)) - 1 ; saturates correctly at +/-1
  return fmaf(2.f, __builtin_amdgcn_rcpf(1.f + __expf(-2.f * z)), -1.f);
}

// ---------------- prep: pack recurrent weights to fp16 pairs ----------------
// Layout keyed for gru_rec's coalesced load: idx = p*1024 + j*4 + s,
// value = ( W[2*(32s+p)][j], W[2*(32s+p)+1][j] )  -- thread tid=4j+s loads
// WU[p] = w2[p*1024 + tid], perfectly coalesced.
__global__ void prep_w(const float* __restrict__ wuc, const float* __restrict__ wrc,
                       const float* __restrict__ wcc,
                       h2* __restrict__ wu2, h2* __restrict__ wr2, h2* __restrict__ wc2) {
  int idx = blockIdx.x * 256 + threadIdx.x;   // 0..32767
  int p = idx >> 10;         // 0..31 local pair index
  int j = (idx >> 2) & 255;  // unit
  int s = idx & 3;           // slice
  int e0 = 2 * (32 * s + p); // absolute k-row
  int k0 = e0 * U_DIM + j;
  int k1 = (e0 + 1) * U_DIM + j;
  wu2[idx] = h2{(_Float16)wuc[k0], (_Float16)wuc[k1]};
  wr2[idx] = h2{(_Float16)wrc[k0], (_Float16)wrc[k1]};
  wc2[idx] = h2{(_Float16)wcc[k0], (_Float16)wcc[k1]};
}

// ---------------- xproj GEMM (fp32): out[r][j] = x_row(r) . W[:,j] ----------
#define TR 128
#define TCOL 128
#define KS 16

__global__ __launch_bounds__(256, 2)
void xproj_gemm(const float* __restrict__ x,
                const float* __restrict__ Wu, const float* __restrict__ Wr,
                const float* __restrict__ Wc,
                const float* __restrict__ Bu, const float* __restrict__ Br,
                const float* __restrict__ Bc,
                float* __restrict__ XU, float* __restrict__ XR, float* __restrict__ XC,
                int t0, int len) {
  const float* W; const float* B; float* O;
  if (blockIdx.z == 0)      { W = Wu; B = Bu; O = XU; }
  else if (blockIdx.z == 1) { W = Wr; B = Br; O = XR; }
  else                      { W = Wc; B = Bc; O = XC; }

  __shared__ float a_sh[KS][TR + 4];
  __shared__ float b_sh[KS][TCOL + 4];

  const int tid = threadIdx.x;
  const int tx = tid & 15, ty = tid >> 4;
  const int r0 = blockIdx.x * TR;
  const int c0 = blockIdx.y * TCOL;

  const int arow = tid >> 1;
  const int ak0  = (tid & 1) * 8;
  const int r    = r0 + arow;
  const int mm   = r / len;
  const int tc   = r - mm * len;
  const float* xrow = x + ((size_t)mm * T_DIM + (size_t)(t0 + tc)) * U_DIM;

  const int bkr = tid >> 4;
  const int bc0 = (tid & 15) * 8;

  float acc[8][8];
#pragma unroll
  for (int i = 0; i < 8; ++i)
#pragma unroll
    for (int q = 0; q < 8; ++q) acc[i][q] = 0.f;

  for (int kk = 0; kk < U_DIM; kk += KS) {
    float4 va0 = *(const float4*)(xrow + kk + ak0);
    float4 va1 = *(const float4*)(xrow + kk + ak0 + 4);
    float4 wb0 = *(const float4*)(W + (size_t)(kk + bkr) * U_DIM + c0 + bc0);
    float4 wb1 = *(const float4*)(W + (size_t)(kk + bkr) * U_DIM + c0 + bc0 + 4);
    __syncthreads();
    a_sh[ak0 + 0][arow] = va0.x; a_sh[ak0 + 1][arow] = va0.y;
    a_sh[ak0 + 2][arow] = va0.z; a_sh[ak0 + 3][arow] = va0.w;
    a_sh[ak0 + 4][arow] = va1.x; a_sh[ak0 + 5][arow] = va1.y;
    a_sh[ak0 + 6][arow] = va1.z; a_sh[ak0 + 7][arow] = va1.w;
    *(float4*)&b_sh[bkr][bc0]     = wb0;
    *(float4*)&b_sh[bkr][bc0 + 4] = wb1;
    __syncthreads();
#pragma unroll
    for (int k = 0; k < KS; ++k) {
      float4 av0 = *(const float4*)&a_sh[k][ty * 8];
      float4 av1 = *(const float4*)&a_sh[k][ty * 8 + 4];
      float4 bv0 = *(const float4*)&b_sh[k][tx * 8];
      float4 bv1 = *(const float4*)&b_sh[k][tx * 8 + 4];
      float aa[8] = {av0.x, av0.y, av0.z, av0.w, av1.x, av1.y, av1.z, av1.w};
      float bb[8] = {bv0.x, bv0.y, bv0.z, bv0.w, bv1.x, bv1.y, bv1.z, bv1.w};
#pragma unroll
      for (int i = 0; i < 8; ++i)
#pragma unroll
        for (int q = 0; q < 8; ++q)
          acc[i][q] = fmaf(aa[i], bb[q], acc[i][q]);
    }
  }

  float4 bi0 = *(const float4*)(B + c0 + tx * 8);
  float4 bi1 = *(const float4*)(B + c0 + tx * 8 + 4);
  float bb2[8] = {bi0.x, bi0.y, bi0.z, bi0.w, bi1.x, bi1.y, bi1.z, bi1.w};
#pragma unroll
  for (int i = 0; i < 8; ++i) {
    int rr = r0 + ty * 8 + i;
    float4 o0 = {acc[i][0] + bb2[0], acc[i][1] + bb2[1], acc[i][2] + bb2[2], acc[i][3] + bb2[3]};
    float4 o1 = {acc[i][4] + bb2[4], acc[i][5] + bb2[5], acc[i][6] + bb2[6], acc[i][7] + bb2[7]};
    *(float4*)(O + (size_t)rr * U_DIM + c0 + tx * 8)     = o0;
    *(float4*)(O + (size_t)rr * U_DIM + c0 + tx * 8 + 4) = o1;
  }
}

// ---------------- recurrence: 1 WG (1024 thr) per batch row -----------------
// tid = 4j+s: 4 threads per unit j, each owns k-slice [64s, 64s+64).
// 16 waves/block = 4 waves/SIMD resident; weights in 96 VGPRs/thread.
__global__ __launch_bounds__(1024, 4)
void gru_rec(const float* __restrict__ XU, const float* __restrict__ XR,
             const float* __restrict__ XC,
             const h2* __restrict__ wu2, const h2* __restrict__ wr2,
             const h2* __restrict__ wc2,
             const float* __restrict__ c_in, float* __restrict__ c_out, int len) {
  const int m = blockIdx.x;
  const int tid = threadIdx.x;
  const int j = tid >> 2;
  const int s = tid & 3;

  __shared__ h8 ch8[32];  // c state, fp16
  __shared__ h8 hh8[32];  // g_r * c, fp16

  h2 WU[32], WR[32], WC[32];
#pragma unroll
  for (int p = 0; p < 32; ++p) {
    WU[p] = wu2[p * 1024 + tid];   // coalesced: layout keyed [p][j][s]
    WR[p] = wr2[p * 1024 + tid];
    WC[p] = wc2[p * 1024 + tid];
  }

  // all 4 lanes of a quad track identical cj (same loads, same math)
  float cj = c_in[m * U_DIM + j];
  if (s == 0) ((_Float16*)ch8)[j] = (_Float16)cj;

  const float* XUb = XU + (size_t)m * len * U_DIM;
  const float* XRb = XR + (size_t)m * len * U_DIM;
  const float* XCb = XC + (size_t)m * len * U_DIM;

  int off = j;
  float xuv = XUb[off], xrv = XRb[off], xcv = XCb[off];

  __syncthreads();

  for (int t = 0; t < len; ++t) {
    // prefetch next step's x while computing this step
    int offn = off + ((t + 1 < len) ? U_DIM : 0);
    float nxu = XUb[offn], nxr = XRb[offn], nxc = XCb[offn];

    // pass 1: pu, pr over slice s (XOR-staggered g -> conflict-free LDS)
    float pu0 = 0.f, pu1 = 0.f, pr0 = 0.f, pr1 = 0.f;
#pragma unroll
    for (int gg = 0; gg < 8; ++gg) {
      int g = gg ^ (s << 1);
      h8 cv = ch8[8 * s + g];
#pragma unroll
      for (int q = 0; q < 4; ++q) {
        h2 cp = {cv[2 * q], cv[2 * q + 1]};
        if (gg & 1) { pu1 = fdot2f(cp, WU[4 * g + q], pu1); pr1 = fdot2f(cp, WR[4 * g + q], pr1); }
        else        { pu0 = fdot2f(cp, WU[4 * g + q], pu0); pr0 = fdot2f(cp, WR[4 * g + q], pr0); }
      }
    }
    float pu = pu0 + pu1;
    pu += __shfl_xor(pu, 1);
    pu += __shfl_xor(pu, 2);
    float pr = pr0 + pr1;
    pr += __shfl_xor(pr, 1);
    pr += __shfl_xor(pr, 2);

    float gu = fast_sigmoid(pu + xuv);
    float gr = fast_sigmoid(pr + xrv);
    if (s == 0) ((_Float16*)hh8)[j] = (_Float16)(gr * cj);
    __syncthreads();

    // pass 2: pc over (g_r * c)
    float pc0 = 0.f, pc1 = 0.f;
#pragma unroll
    for (int gg = 0; gg < 8; ++gg) {
      int g = gg ^ (s << 1);
      h8 hv = hh8[8 * s + g];
#pragma unroll
      for (int q = 0; q < 4; ++q) {
        h2 hp = {hv[2 * q], hv[2 * q + 1]};
        if (gg & 1) pc1 = fdot2f(hp, WC[4 * g + q], pc1);
        else        pc0 = fdot2f(hp, WC[4 * g + q], pc0);
      }
    }
    float pc = pc0 + pc1;
    pc += __shfl_xor(pc, 1);
    pc += __shfl_xor(pc, 2);

    float cand = fast_tanh(pc + xcv);
    cj = fmaf(gu, cand - cj, cj);  // gu*cand + (1-gu)*cj
    if (s == 0) ((_Float16*)ch8)[j] = (_Float16)cj;

    xuv = nxu; xrv = nxr; xcv = nxc; off = offn;
    __syncthreads();
  }

  if (s == 0) c_out[m * U_DIM + j] = cj;
}

// ---------------- host ------------------------------------------------------
extern "C" void kernel_launch(void* const* d_in, const int* in_sizes, int n_in,
                              void* d_out, int out_size, void* d_ws, size_t ws_size,
                              hipStream_t stream) {
  const float* x   = (const float*)d_in[0];
  const float* a0  = (const float*)d_in[1];
  const float* wcx = (const float*)d_in[2];
  const float* wcc = (const float*)d_in[3];
  const float* bc  = (const float*)d_in[4];
  const float* wux = (const float*)d_in[5];
  const float* wuc = (const float*)d_in[6];
  const float* bu  = (const float*)d_in[7];
  const float* wrx = (const float*)d_in[8];
  const float* wrc = (const float*)d_in[9];
  const float* br  = (const float*)d_in[10];
  float* out = (float*)d_out;

  const size_t W16_BYTES = 3ull * 128 * 256 * sizeof(h2);  // 393216
  size_t avail = (ws_size > W16_BYTES) ? (ws_size - W16_BYTES) : 0;
  const size_t perT = 3ull * M_DIM * U_DIM * sizeof(float);
  int Tc = (int)(avail / perT);
  if (Tc > T_DIM) Tc = T_DIM;
  if (Tc < 1) Tc = 1;
  int nch = (T_DIM + Tc - 1) / Tc;
  Tc = (T_DIM + nch - 1) / nch;

  float* XU = (float*)d_ws;
  float* XR = XU + (size_t)M_DIM * Tc * U_DIM;
  float* XC = XR + (size_t)M_DIM * Tc * U_DIM;
  h2* W16 = (h2*)(XC + (size_t)M_DIM * Tc * U_DIM);
  h2* wu2 = W16;
  h2* wr2 = W16 + 32768;
  h2* wc2 = W16 + 65536;

  prep_w<<<128, 256, 0, stream>>>(wuc, wrc, wcc, wu2, wr2, wc2);

  for (int t0 = 0; t0 < T_DIM; t0 += Tc) {
    int lenc = (T_DIM - t0) < Tc ? (T_DIM - t0) : Tc;
    dim3 g((M_DIM * lenc) / TR, U_DIM / TCOL, 3);
    xproj_gemm<<<g, 256, 0, stream>>>(x, wux, wrx, wcx, bu, br, bc,
                                      XU, XR, XC, t0, lenc);
    gru_rec<<<M_DIM, 1024, 0, stream>>>(XU, XR, XC, wu2, wr2, wc2,
                                        (t0 == 0 ? a0 : out), out, lenc);
  }
}

// Round 3
// 1441.580 us; speedup vs baseline: 3.5831x; 3.5831x over previous
//
#include <hip/hip_runtime.h>

typedef _Float16 h2 __attribute__((ext_vector_type(2)));
typedef _Float16 h8 __attribute__((ext_vector_type(8)));

#define U_DIM 256
#define M_DIM 256
#define T_DIM 512

#if defined(__has_builtin)
#if __has_builtin(__builtin_amdgcn_fdot2)
#define HAVE_FDOT2 1
#endif
#endif

__device__ __forceinline__ float fdot2f(h2 a, h2 b, float c) {
#ifdef HAVE_FDOT2
  return __builtin_amdgcn_fdot2(a, b, c, false);
#else
  return fmaf((float)a[0], (float)b[0], fmaf((float)a[1], (float)b[1], c));
#endif
}

__device__ __forceinline__ float fast_sigmoid(float z) {
  return __builtin_amdgcn_rcpf(1.f + __expf(-z));
}
__device__ __forceinline__ float fast_tanh(float z) {
  return fmaf(2.f, __builtin_amdgcn_rcpf(1.f + __expf(-2.f * z)), -1.f);
}

// ---------------- prep: pack recurrent weights to fp16 h8 chunks ------------
// w16 layout: [mtx][tid][v], mtx in {U,R,C}, tid=2j+s in [0,512), v in [0,16).
// w16[((mtx*512)+tid)*16+v][e] = (fp16) W[128*s + 8*v + e][j]
__global__ void prep_w(const float* __restrict__ wuc, const float* __restrict__ wrc,
                       const float* __restrict__ wcc, h8* __restrict__ w16) {
  int idx = blockIdx.x * 256 + threadIdx.x;   // 0..24575
  int mtx = idx >> 13;
  int rem = idx & 8191;
  int tid = rem >> 4;
  int v   = rem & 15;
  int j = tid >> 1, s = tid & 1;
  const float* W = (mtx == 0) ? wuc : ((mtx == 1) ? wrc : wcc);
  int k0 = 128 * s + 8 * v;
  h8 o;
#pragma unroll
  for (int e = 0; e < 8; ++e) o[e] = (_Float16)W[(size_t)(k0 + e) * U_DIM + j];
  w16[idx] = o;
}

// ---------------- xproj GEMM (fp32), unchanged from round 1 -----------------
#define TR 128
#define TCOL 128
#define KS 16

__global__ __launch_bounds__(256, 2)
void xproj_gemm(const float* __restrict__ x,
                const float* __restrict__ Wu, const float* __restrict__ Wr,
                const float* __restrict__ Wc,
                const float* __restrict__ Bu, const float* __restrict__ Br,
                const float* __restrict__ Bc,
                float* __restrict__ XU, float* __restrict__ XR, float* __restrict__ XC,
                int t0, int len) {
  const float* W; const float* B; float* O;
  if (blockIdx.z == 0)      { W = Wu; B = Bu; O = XU; }
  else if (blockIdx.z == 1) { W = Wr; B = Br; O = XR; }
  else                      { W = Wc; B = Bc; O = XC; }

  __shared__ float a_sh[KS][TR + 4];
  __shared__ float b_sh[KS][TCOL + 4];

  const int tid = threadIdx.x;
  const int tx = tid & 15, ty = tid >> 4;
  const int r0 = blockIdx.x * TR;
  const int c0 = blockIdx.y * TCOL;

  const int arow = tid >> 1;
  const int ak0  = (tid & 1) * 8;
  const int r    = r0 + arow;
  const int mm   = r / len;
  const int tc   = r - mm * len;
  const float* xrow = x + ((size_t)mm * T_DIM + (size_t)(t0 + tc)) * U_DIM;

  const int bkr = tid >> 4;
  const int bc0 = (tid & 15) * 8;

  float acc[8][8];
#pragma unroll
  for (int i = 0; i < 8; ++i)
#pragma unroll
    for (int q = 0; q < 8; ++q) acc[i][q] = 0.f;

  for (int kk = 0; kk < U_DIM; kk += KS) {
    float4 va0 = *(const float4*)(xrow + kk + ak0);
    float4 va1 = *(const float4*)(xrow + kk + ak0 + 4);
    float4 wb0 = *(const float4*)(W + (size_t)(kk + bkr) * U_DIM + c0 + bc0);
    float4 wb1 = *(const float4*)(W + (size_t)(kk + bkr) * U_DIM + c0 + bc0 + 4);
    __syncthreads();
    a_sh[ak0 + 0][arow] = va0.x; a_sh[ak0 + 1][arow] = va0.y;
    a_sh[ak0 + 2][arow] = va0.z; a_sh[ak0 + 3][arow] = va0.w;
    a_sh[ak0 + 4][arow] = va1.x; a_sh[ak0 + 5][arow] = va1.y;
    a_sh[ak0 + 6][arow] = va1.z; a_sh[ak0 + 7][arow] = va1.w;
    *(float4*)&b_sh[bkr][bc0]     = wb0;
    *(float4*)&b_sh[bkr][bc0 + 4] = wb1;
    __syncthreads();
#pragma unroll
    for (int k = 0; k < KS; ++k) {
      float4 av0 = *(const float4*)&a_sh[k][ty * 8];
      float4 av1 = *(const float4*)&a_sh[k][ty * 8 + 4];
      float4 bv0 = *(const float4*)&b_sh[k][tx * 8];
      float4 bv1 = *(const float4*)&b_sh[k][tx * 8 + 4];
      float aa[8] = {av0.x, av0.y, av0.z, av0.w, av1.x, av1.y, av1.z, av1.w};
      float bb[8] = {bv0.x, bv0.y, bv0.z, bv0.w, bv1.x, bv1.y, bv1.z, bv1.w};
#pragma unroll
      for (int i = 0; i < 8; ++i)
#pragma unroll
        for (int q = 0; q < 8; ++q)
          acc[i][q] = fmaf(aa[i], bb[q], acc[i][q]);
    }
  }

  float4 bi0 = *(const float4*)(B + c0 + tx * 8);
  float4 bi1 = *(const float4*)(B + c0 + tx * 8 + 4);
  float bb2[8] = {bi0.x, bi0.y, bi0.z, bi0.w, bi1.x, bi1.y, bi1.z, bi1.w};
#pragma unroll
  for (int i = 0; i < 8; ++i) {
    int rr = r0 + ty * 8 + i;
    float4 o0 = {acc[i][0] + bb2[0], acc[i][1] + bb2[1], acc[i][2] + bb2[2], acc[i][3] + bb2[3]};
    float4 o1 = {acc[i][4] + bb2[4], acc[i][5] + bb2[5], acc[i][6] + bb2[6], acc[i][7] + bb2[7]};
    *(float4*)(O + (size_t)rr * U_DIM + c0 + tx * 8)     = o0;
    *(float4*)(O + (size_t)rr * U_DIM + c0 + tx * 8 + 4) = o1;
  }
}

// ---------------- recurrence: 512 thr/block, 2 thr per unit -----------------
// tid=2j+s; thread owns k-slice [128s,128s+128) = 16 h8 per matrix, held in
// 48 NAMED h8 values (192 VGPRs) -- named SSA, not arrays, so regalloc keeps
// them resident (round-1/2 arrays were spilled; FETCH_SIZE proved it).
__global__ __launch_bounds__(512, 2)
void gru_rec(const float* __restrict__ XU, const float* __restrict__ XR,
             const float* __restrict__ XC,
             const h8* __restrict__ w16,
             const float* __restrict__ c_in, float* __restrict__ c_out, int len) {
  const int m = blockIdx.x;
  const int tid = threadIdx.x;
  const int j = tid >> 1;
  const int s = tid & 1;
  const int cb = s * 16;

  __shared__ h8 ch8[32];  // c state, fp16, indexed by k-chunk
  __shared__ h8 hh8[32];  // g_r * c, fp16

  const h8* wub = w16 + (size_t)tid * 16;
  const h8* wrb = wub + 8192;
  const h8* wcb = wub + 16384;

#define DECL_W(i) h8 wu##i = wub[i]; h8 wr##i = wrb[i]; h8 wc##i = wcb[i];
  DECL_W(0)  DECL_W(1)  DECL_W(2)  DECL_W(3)
  DECL_W(4)  DECL_W(5)  DECL_W(6)  DECL_W(7)
  DECL_W(8)  DECL_W(9)  DECL_W(10) DECL_W(11)
  DECL_W(12) DECL_W(13) DECL_W(14) DECL_W(15)
#undef DECL_W

  float cj = c_in[m * U_DIM + j];
  if (s == 0) ((_Float16*)ch8)[j] = (_Float16)cj;

  const float* XUb = XU + (size_t)m * len * U_DIM;
  const float* XRb = XR + (size_t)m * len * U_DIM;
  const float* XCb = XC + (size_t)m * len * U_DIM;

  int off = j;
  float xuv = XUb[off], xrv = XRb[off], xcv = XCb[off];

  __syncthreads();

  for (int t = 0; t < len; ++t) {
    int offn = off + ((t + 1 < len) ? U_DIM : 0);
    float nxu = XUb[offn], nxr = XRb[offn], nxc = XCb[offn];

    float pu0 = 0.f, pu1 = 0.f, pr0 = 0.f, pr1 = 0.f;
#define PASS1(i) { h8 cv = ch8[cb + i];                                   \
    pu0 = fdot2f(h2{cv[0], cv[1]}, h2{wu##i[0], wu##i[1]}, pu0);          \
    pr0 = fdot2f(h2{cv[0], cv[1]}, h2{wr##i[0], wr##i[1]}, pr0);          \
    pu1 = fdot2f(h2{cv[2], cv[3]}, h2{wu##i[2], wu##i[3]}, pu1);          \
    pr1 = fdot2f(h2{cv[2], cv[3]}, h2{wr##i[2], wr##i[3]}, pr1);          \
    pu0 = fdot2f(h2{cv[4], cv[5]}, h2{wu##i[4], wu##i[5]}, pu0);          \
    pr0 = fdot2f(h2{cv[4], cv[5]}, h2{wr##i[4], wr##i[5]}, pr0);          \
    pu1 = fdot2f(h2{cv[6], cv[7]}, h2{wu##i[6], wu##i[7]}, pu1);          \
    pr1 = fdot2f(h2{cv[6], cv[7]}, h2{wr##i[6], wr##i[7]}, pr1); }
    PASS1(0)  PASS1(1)  PASS1(2)  PASS1(3)
    PASS1(4)  PASS1(5)  PASS1(6)  PASS1(7)
    PASS1(8)  PASS1(9)  PASS1(10) PASS1(11)
    PASS1(12) PASS1(13) PASS1(14) PASS1(15)
#undef PASS1

    float pu = pu0 + pu1;
    pu += __shfl_xor(pu, 1);
    float pr = pr0 + pr1;
    pr += __shfl_xor(pr, 1);

    float gu = fast_sigmoid(pu + xuv);
    float gr = fast_sigmoid(pr + xrv);
    if (s == 0) ((_Float16*)hh8)[j] = (_Float16)(gr * cj);
    __syncthreads();

    float pc0 = 0.f, pc1 = 0.f;
#define PASS2(i) { h8 hv = hh8[cb + i];                                   \
    pc0 = fdot2f(h2{hv[0], hv[1]}, h2{wc##i[0], wc##i[1]}, pc0);          \
    pc1 = fdot2f(h2{hv[2], hv[3]}, h2{wc##i[2], wc##i[3]}, pc1);          \
    pc0 = fdot2f(h2{hv[4], hv[5]}, h2{wc##i[4], wc##i[5]}, pc0);          \
    pc1 = fdot2f(h2{hv[6], hv[7]}, h2{wc##i[6], wc##i[7]}, pc1); }
    PASS2(0)  PASS2(1)  PASS2(2)  PASS2(3)
    PASS2(4)  PASS2(5)  PASS2(6)  PASS2(7)
    PASS2(8)  PASS2(9)  PASS2(10) PASS2(11)
    PASS2(12) PASS2(13) PASS2(14) PASS2(15)
#undef PASS2

    float pc = pc0 + pc1;
    pc += __shfl_xor(pc, 1);

    float cand = fast_tanh(pc + xcv);
    cj = fmaf(gu, cand - cj, cj);
    if (s == 0) ((_Float16*)ch8)[j] = (_Float16)cj;

    xuv = nxu; xrv = nxr; xcv = nxc; off = offn;
    __syncthreads();
  }

  if (s == 0) c_out[m * U_DIM + j] = cj;
}

// ---------------- host ------------------------------------------------------
extern "C" void kernel_launch(void* const* d_in, const int* in_sizes, int n_in,
                              void* d_out, int out_size, void* d_ws, size_t ws_size,
                              hipStream_t stream) {
  const float* x   = (const float*)d_in[0];
  const float* a0  = (const float*)d_in[1];
  const float* wcx = (const float*)d_in[2];
  const float* wcc = (const float*)d_in[3];
  const float* bc  = (const float*)d_in[4];
  const float* wux = (const float*)d_in[5];
  const float* wuc = (const float*)d_in[6];
  const float* bu  = (const float*)d_in[7];
  const float* wrx = (const float*)d_in[8];
  const float* wrc = (const float*)d_in[9];
  const float* br  = (const float*)d_in[10];
  float* out = (float*)d_out;

  const size_t W16_BYTES = 3ull * 512 * 16 * sizeof(h8);  // 393216
  size_t avail = (ws_size > W16_BYTES) ? (ws_size - W16_BYTES) : 0;
  const size_t perT = 3ull * M_DIM * U_DIM * sizeof(float);
  int Tc = (int)(avail / perT);
  if (Tc > T_DIM) Tc = T_DIM;
  if (Tc < 1) Tc = 1;
  int nch = (T_DIM + Tc - 1) / Tc;
  Tc = (T_DIM + nch - 1) / nch;

  float* XU = (float*)d_ws;
  float* XR = XU + (size_t)M_DIM * Tc * U_DIM;
  float* XC = XR + (size_t)M_DIM * Tc * U_DIM;
  h8* w16 = (h8*)(XC + (size_t)M_DIM * Tc * U_DIM);

  prep_w<<<96, 256, 0, stream>>>(wuc, wrc, wcc, w16);

  for (int t0 = 0; t0 < T_DIM; t0 += Tc) {
    int lenc = (T_DIM - t0) < Tc ? (T_DIM - t0) : Tc;
    dim3 g((M_DIM * lenc) / TR, U_DIM / TCOL, 3);
    xproj_gemm<<<g, 256, 0, stream>>>(x, wux, wrx, wcx, bu, br, bc,
                                      XU, XR, XC, t0, lenc);
    gru_rec<<<M_DIM, 512, 0, stream>>>(XU, XR, XC, w16,
                                       (t0 == 0 ? a0 : out), out, lenc);
  }
}

// Round 4
// 1017.152 us; speedup vs baseline: 5.0782x; 1.4173x over previous
//
#include <hip/hip_runtime.h>

typedef _Float16 h2 __attribute__((ext_vector_type(2)));
typedef _Float16 h8 __attribute__((ext_vector_type(8)));
typedef float f4v __attribute__((ext_vector_type(4)));

#define U_DIM 256
#define M_DIM 256
#define T_DIM 512

#if defined(__has_builtin)
#if __has_builtin(__builtin_amdgcn_fdot2)
#define HAVE_FDOT2 1
#endif
#endif

__device__ __forceinline__ float fdot2f(h2 a, h2 b, float c) {
#ifdef HAVE_FDOT2
  return __builtin_amdgcn_fdot2(a, b, c, false);
#else
  return fmaf((float)a[0], (float)b[0], fmaf((float)a[1], (float)b[1], c));
#endif
}

__device__ __forceinline__ float fast_sigmoid(float z) {
  return __builtin_amdgcn_rcpf(1.f + __expf(-z));
}
__device__ __forceinline__ float fast_tanh(float z) {
  return fmaf(2.f, __builtin_amdgcn_rcpf(1.f + __expf(-2.f * z)), -1.f);
}

// ---------------- prep: x fp32 -> fp16 (same [M][T][256] layout) ------------
__global__ void conv_x(const float* __restrict__ x, h8* __restrict__ x16, int n8) {
  int i = blockIdx.x * 256 + threadIdx.x;
  if (i >= n8) return;
  const float4* p = (const float4*)(x + (size_t)i * 8);
  float4 v0 = p[0], v1 = p[1];
  h8 o = {(_Float16)v0.x, (_Float16)v0.y, (_Float16)v0.z, (_Float16)v0.w,
          (_Float16)v1.x, (_Float16)v1.y, (_Float16)v1.z, (_Float16)v1.w};
  x16[i] = o;
}

// ------- prep: x-projection weights -> fp16 TRANSPOSED [mtx][n][k] ----------
// wt16[((mtx*256+n)*32 + kv)][e] = (fp16) W[kv*8+e][n]
__global__ void prep_xw(const float* __restrict__ wux, const float* __restrict__ wrx,
                        const float* __restrict__ wcx, h8* __restrict__ wt16) {
  int idx = blockIdx.x * 256 + threadIdx.x;   // 0..24575
  int mtx = idx >> 13;
  int rem = idx & 8191;
  int n = rem >> 5;
  int kv = rem & 31;
  const float* W = (mtx == 0) ? wux : ((mtx == 1) ? wrx : wcx);
  h8 o;
#pragma unroll
  for (int e = 0; e < 8; ++e) o[e] = (_Float16)W[(size_t)(kv * 8 + e) * U_DIM + n];
  wt16[idx] = o;
}

// ---------------- prep: recurrent weights fp16, [mtx][tid][v] ---------------
__global__ void prep_w(const float* __restrict__ wuc, const float* __restrict__ wrc,
                       const float* __restrict__ wcc, h8* __restrict__ w16) {
  int idx = blockIdx.x * 256 + threadIdx.x;   // 0..24575
  int mtx = idx >> 13;
  int rem = idx & 8191;
  int tid = rem >> 4;
  int v   = rem & 15;
  int j = tid >> 1, s = tid & 1;
  const float* W = (mtx == 0) ? wuc : ((mtx == 1) ? wrc : wcc);
  int k0 = 128 * s + 8 * v;
  h8 o;
#pragma unroll
  for (int e = 0; e < 8; ++e) o[e] = (_Float16)W[(size_t)(k0 + e) * U_DIM + j];
  w16[idx] = o;
}

// ---------------- xproj via fp16 MFMA: O[r][n] = x16[r,:] . W[:,n] + b ------
// 128x128 tile, 256 thr (4 waves), wave w owns rows [32w,32w+32).
// A-frag: A[m=lane&15][k=quad*8+j]; B-frag: B[k=quad*8+j][n=lane&15];
// C/D: col=lane&15, row=quad*4+reg  (verified mappings, learn_hip m89/m120).
__global__ __launch_bounds__(256, 2)
void xproj_mfma(const h8* __restrict__ x16, const h8* __restrict__ wt16,
                const float* __restrict__ Bu, const float* __restrict__ Br,
                const float* __restrict__ Bc,
                float* __restrict__ XU, float* __restrict__ XR, float* __restrict__ XC,
                int t0, int len) {
  const int mtx = blockIdx.z;
  const float* Bv = (mtx == 0) ? Bu : ((mtx == 1) ? Br : Bc);
  float* O = (mtx == 0) ? XU : ((mtx == 1) ? XR : XC);
  const h8* W = wt16 + (size_t)mtx * 256 * 32;

  __shared__ _Float16 a_sh[128][40];  // rows padded 32->40 fp16 (80 B, 16B-aligned)
  __shared__ _Float16 b_sh[128][40];

  const int tid = threadIdx.x;
  const int r0 = blockIdx.x * 128;
  const int c0 = blockIdx.y * 128;

  // staging: thread -> (row, k-half)
  const int srow = tid >> 1;
  const int spart = tid & 1;
  const int r = r0 + srow;
  const int mm = r / len;
  const int tc = r - mm * len;
  const h8* arow = x16 + ((size_t)mm * T_DIM + (size_t)(t0 + tc)) * 32;
  const h8* brow = W + (size_t)(c0 + srow) * 32;

  const int lane = tid & 63;
  const int w = tid >> 6;
  const int quad = lane >> 4;
  const int mrow = lane & 15;

  f4v acc[2][8];
#pragma unroll
  for (int fr = 0; fr < 2; ++fr)
#pragma unroll
    for (int fc = 0; fc < 8; ++fc) acc[fr][fc] = f4v{0.f, 0.f, 0.f, 0.f};

  for (int k8 = 0; k8 < 32; k8 += 4) {  // k advances 32 halves per iter
    h8 a0 = arow[k8 + 2 * spart];
    h8 a1 = arow[k8 + 2 * spart + 1];
    h8 b0 = brow[k8 + 2 * spart];
    h8 b1 = brow[k8 + 2 * spart + 1];
    __syncthreads();
    *(h8*)&a_sh[srow][spart * 16]     = a0;
    *(h8*)&a_sh[srow][spart * 16 + 8] = a1;
    *(h8*)&b_sh[srow][spart * 16]     = b0;
    *(h8*)&b_sh[srow][spart * 16 + 8] = b1;
    __syncthreads();
    h8 af0 = *(const h8*)&a_sh[32 * w + mrow][quad * 8];
    h8 af1 = *(const h8*)&a_sh[32 * w + 16 + mrow][quad * 8];
#pragma unroll
    for (int fc = 0; fc < 8; ++fc) {
      h8 bf = *(const h8*)&b_sh[fc * 16 + mrow][quad * 8];
      acc[0][fc] = __builtin_amdgcn_mfma_f32_16x16x32_f16(af0, bf, acc[0][fc], 0, 0, 0);
      acc[1][fc] = __builtin_amdgcn_mfma_f32_16x16x32_f16(af1, bf, acc[1][fc], 0, 0, 0);
    }
  }

#pragma unroll
  for (int fc = 0; fc < 8; ++fc) {
    int col = c0 + fc * 16 + mrow;
    float bb = Bv[col];
#pragma unroll
    for (int fr = 0; fr < 2; ++fr)
#pragma unroll
      for (int reg = 0; reg < 4; ++reg) {
        int rr = r0 + 32 * w + fr * 16 + quad * 4 + reg;
        O[(size_t)rr * U_DIM + col] = acc[fr][fc][reg] + bb;
      }
  }
}

// ---------------- recurrence: 512 thr/block, 2 thr per unit -----------------
// LDS state arrays padded: s=1 half starts at chunk 17 so the two broadcast
// groups of a wave instruction hit DISJOINT banks (round-3: 1.34e8 conflicts).
__global__ __launch_bounds__(512, 2)
void gru_rec(const float* __restrict__ XU, const float* __restrict__ XR,
             const float* __restrict__ XC,
             const h8* __restrict__ w16,
             const float* __restrict__ c_in, float* __restrict__ c_out, int len) {
  const int m = blockIdx.x;
  const int tid = threadIdx.x;
  const int j = tid >> 1;
  const int s = tid & 1;
  const int cb = s * 17;                    // padded chunk base
  const int wj = j + ((j >> 7) << 3);       // padded elem index for writes

  __shared__ h8 ch8[34];
  __shared__ h8 hh8[34];

  const h8* wub = w16 + (size_t)tid * 16;
  const h8* wrb = wub + 8192;
  const h8* wcb = wub + 16384;

#define DECL_W(i) h8 wu##i = wub[i]; h8 wr##i = wrb[i]; h8 wc##i = wcb[i];
  DECL_W(0)  DECL_W(1)  DECL_W(2)  DECL_W(3)
  DECL_W(4)  DECL_W(5)  DECL_W(6)  DECL_W(7)
  DECL_W(8)  DECL_W(9)  DECL_W(10) DECL_W(11)
  DECL_W(12) DECL_W(13) DECL_W(14) DECL_W(15)
#undef DECL_W

  float cj = c_in[m * U_DIM + j];
  if (s == 0) ((_Float16*)ch8)[wj] = (_Float16)cj;

  const float* XUb = XU + (size_t)m * len * U_DIM;
  const float* XRb = XR + (size_t)m * len * U_DIM;
  const float* XCb = XC + (size_t)m * len * U_DIM;

  int off = j;
  float xuv = XUb[off], xrv = XRb[off], xcv = XCb[off];

  __syncthreads();

  for (int t = 0; t < len; ++t) {
    int offn = off + ((t + 1 < len) ? U_DIM : 0);
    float nxu = XUb[offn], nxr = XRb[offn], nxc = XCb[offn];

    float pu0 = 0.f, pu1 = 0.f, pr0 = 0.f, pr1 = 0.f;
#define PASS1(i) { h8 cv = ch8[cb + i];                                   \
    pu0 = fdot2f(h2{cv[0], cv[1]}, h2{wu##i[0], wu##i[1]}, pu0);          \
    pr0 = fdot2f(h2{cv[0], cv[1]}, h2{wr##i[0], wr##i[1]}, pr0);          \
    pu1 = fdot2f(h2{cv[2], cv[3]}, h2{wu##i[2], wu##i[3]}, pu1);          \
    pr1 = fdot2f(h2{cv[2], cv[3]}, h2{wr##i[2], wr##i[3]}, pr1);          \
    pu0 = fdot2f(h2{cv[4], cv[5]}, h2{wu##i[4], wu##i[5]}, pu0);          \
    pr0 = fdot2f(h2{cv[4], cv[5]}, h2{wr##i[4], wr##i[5]}, pr0);          \
    pu1 = fdot2f(h2{cv[6], cv[7]}, h2{wu##i[6], wu##i[7]}, pu1);          \
    pr1 = fdot2f(h2{cv[6], cv[7]}, h2{wr##i[6], wr##i[7]}, pr1); }
    PASS1(0)  PASS1(1)  PASS1(2)  PASS1(3)
    PASS1(4)  PASS1(5)  PASS1(6)  PASS1(7)
    PASS1(8)  PASS1(9)  PASS1(10) PASS1(11)
    PASS1(12) PASS1(13) PASS1(14) PASS1(15)
#undef PASS1

    float pu = pu0 + pu1;
    pu += __shfl_xor(pu, 1);
    float pr = pr0 + pr1;
    pr += __shfl_xor(pr, 1);

    float gu = fast_sigmoid(pu + xuv);
    float gr = fast_sigmoid(pr + xrv);
    if (s == 0) ((_Float16*)hh8)[wj] = (_Float16)(gr * cj);
    __syncthreads();

    float pc0 = 0.f, pc1 = 0.f;
#define PASS2(i) { h8 hv = hh8[cb + i];                                   \
    pc0 = fdot2f(h2{hv[0], hv[1]}, h2{wc##i[0], wc##i[1]}, pc0);          \
    pc1 = fdot2f(h2{hv[2], hv[3]}, h2{wc##i[2], wc##i[3]}, pc1);          \
    pc0 = fdot2f(h2{hv[4], hv[5]}, h2{wc##i[4], wc##i[5]}, pc0);          \
    pc1 = fdot2f(h2{hv[6], hv[7]}, h2{wc##i[6], wc##i[7]}, pc1); }
    PASS2(0)  PASS2(1)  PASS2(2)  PASS2(3)
    PASS2(4)  PASS2(5)  PASS2(6)  PASS2(7)
    PASS2(8)  PASS2(9)  PASS2(10) PASS2(11)
    PASS2(12) PASS2(13) PASS2(14) PASS2(15)
#undef PASS2

    float pc = pc0 + pc1;
    pc += __shfl_xor(pc, 1);

    float cand = fast_tanh(pc + xcv);
    cj = fmaf(gu, cand - cj, cj);
    if (s == 0) ((_Float16*)ch8)[wj] = (_Float16)cj;

    xuv = nxu; xrv = nxr; xcv = nxc; off = offn;
    __syncthreads();
  }

  if (s == 0) c_out[m * U_DIM + j] = cj;
}

// ---------------- host ------------------------------------------------------
extern "C" void kernel_launch(void* const* d_in, const int* in_sizes, int n_in,
                              void* d_out, int out_size, void* d_ws, size_t ws_size,
                              hipStream_t stream) {
  const float* x   = (const float*)d_in[0];
  const float* a0  = (const float*)d_in[1];
  const float* wcx = (const float*)d_in[2];
  const float* wcc = (const float*)d_in[3];
  const float* bc  = (const float*)d_in[4];
  const float* wux = (const float*)d_in[5];
  const float* wuc = (const float*)d_in[6];
  const float* bu  = (const float*)d_in[7];
  const float* wrx = (const float*)d_in[8];
  const float* wrc = (const float*)d_in[9];
  const float* br  = (const float*)d_in[10];
  float* out = (float*)d_out;

  const size_t x16_bytes = (size_t)M_DIM * T_DIM * U_DIM * 2;  // 67.1 MB
  const size_t wt_bytes  = 3ull * 256 * 32 * 16;               // 384 KB
  const size_t w16_bytes = 3ull * 512 * 16 * 16;               // 384 KB
  const size_t fixed = x16_bytes + wt_bytes + w16_bytes;

  h8* x16  = (h8*)d_ws;
  h8* wt16 = (h8*)((char*)d_ws + x16_bytes);
  h8* w16  = (h8*)((char*)d_ws + x16_bytes + wt_bytes);
  float* XU0 = (float*)((char*)d_ws + fixed);

  size_t avail = (ws_size > fixed) ? (ws_size - fixed) : 0;
  const size_t perT = 3ull * M_DIM * U_DIM * sizeof(float);    // 786 KB / step
  int Tc = (int)(avail / perT);
  if (Tc > T_DIM) Tc = T_DIM;
  if (Tc < 1) Tc = 1;
  int nch = (T_DIM + Tc - 1) / Tc;
  Tc = (T_DIM + nch - 1) / nch;

  float* XU = XU0;
  float* XR = XU + (size_t)M_DIM * Tc * U_DIM;
  float* XC = XR + (size_t)M_DIM * Tc * U_DIM;

  conv_x<<<16384, 256, 0, stream>>>(x, x16, M_DIM * T_DIM * U_DIM / 8);
  prep_xw<<<96, 256, 0, stream>>>(wux, wrx, wcx, wt16);
  prep_w<<<96, 256, 0, stream>>>(wuc, wrc, wcc, w16);

  for (int t0 = 0; t0 < T_DIM; t0 += Tc) {
    int lenc = (T_DIM - t0) < Tc ? (T_DIM - t0) : Tc;
    dim3 g((M_DIM * lenc) / 128, 2, 3);
    xproj_mfma<<<g, 256, 0, stream>>>(x16, wt16, bu, br, bc,
                                      XU, XR, XC, t0, lenc);
    gru_rec<<<M_DIM, 512, 0, stream>>>(XU, XR, XC, w16,
                                       (t0 == 0 ? a0 : out), out, lenc);
  }
}